// Round 16
// baseline (127.171 us; speedup 1.0000x reference)
//
#include <hip/hip_runtime.h>
#include <hip/hip_bf16.h>

constexpr int S_LEN   = 4096;
constexpr int EMB     = 768;
constexpr int NH      = 12;
constexpr int DK      = 64;
constexpr int QKV_DIM = 3 * EMB;   // 2304
constexpr int NSPLIT  = 2;
constexpr int TSPLIT  = S_LEN / NSPLIT;  // 2048

typedef short bf16x8 __attribute__((ext_vector_type(8)));
typedef float f32x4  __attribute__((ext_vector_type(4)));
typedef unsigned short u16;

// f32 -> bf16 round-to-nearest-even (cold paths / GEMM epilogues)
__device__ inline u16 f2bf(float x) {
  unsigned u = __float_as_uint(x);
  unsigned r = u + 0x7fffu + ((u >> 16) & 1u);
  return (u16)(r >> 16);
}
__device__ inline float bf2f(u16 h) {
  return __uint_as_float(((unsigned)h) << 16);
}

__device__ inline void gld16(unsigned* lds, const unsigned* g) {
  __builtin_amdgcn_global_load_lds(
      (const __attribute__((address_space(1))) unsigned*)g,
      (__attribute__((address_space(3))) unsigned*)lds, 16, 0, 0);
}

// raw v_exp_f32 (2^x); scores are bounded, no special-case handling needed
__device__ inline float fast_exp2(float x) {
  float r;
  asm("v_exp_f32 %0, %1" : "=v"(r) : "v"(x));
  return r;
}

#define LOG2E 1.4426950408889634f

// ---------------------------------------------------------------------------
// fused fp32 -> bf16 casts for x, w_qkv, w_out (one launch, 3 grid segments)
// ---------------------------------------------------------------------------
__global__ __launch_bounds__(256) void cast_bf16_fused(
    const float* __restrict__ s0, u16* __restrict__ d0, int n0,   // 512 blocks
    const float* __restrict__ s1, u16* __restrict__ d1, int n1,   // 256 blocks
    const float* __restrict__ s2, u16* __restrict__ d2, int n2)   // 128 blocks
{
  const float* src; u16* dst; int n8, b0, nb;
  if (blockIdx.x < 512)      { src = s0; dst = d0; n8 = n0; b0 = 0;   nb = 512; }
  else if (blockIdx.x < 768) { src = s1; dst = d1; n8 = n1; b0 = 512; nb = 256; }
  else                       { src = s2; dst = d2; n8 = n2; b0 = 768; nb = 128; }
  for (int i = (blockIdx.x - b0) * 256 + threadIdx.x; i < n8; i += nb * 256) {
    float4 a = reinterpret_cast<const float4*>(src)[2 * i + 0];
    float4 b = reinterpret_cast<const float4*>(src)[2 * i + 1];
    ushort4 h0, h1;
    const float* ap = reinterpret_cast<const float*>(&a);
    const float* bp = reinterpret_cast<const float*>(&b);
#pragma unroll
    for (int j = 0; j < 4; ++j) {
      reinterpret_cast<u16*>(&h0)[j] = f2bf(ap[j]);
      reinterpret_cast<u16*>(&h1)[j] = f2bf(bp[j]);
    }
    reinterpret_cast<ushort4*>(dst)[2 * i + 0] = h0;
    reinterpret_cast<ushort4*>(dst)[2 * i + 1] = h1;
  }
}

// ---------------------------------------------------------------------------
// bf16 NT-GEMM (QKV projection): C[M,N] = A[M,K] @ B[N,K]^T, fp32 accum.
// bf16 out; Q cols (<EMB) scaled by 0.125*log2(e).
// ---------------------------------------------------------------------------
__global__ __launch_bounds__(256) void gemm_qkv(
    const u16* __restrict__ A, const u16* __restrict__ B,
    u16* __restrict__ Cb, int M, int N, int K)
{
  __shared__ __align__(16) u16 sA[128 * 64];
  __shared__ __align__(16) u16 sB[128 * 64];

  const int tid  = threadIdx.x;
  const int w    = tid >> 6;
  const int l    = tid & 63;
  const int lg   = l >> 4;
  const int lr   = l & 15;
  const int wr   = w >> 1;
  const int wc   = w & 1;
  const int brow = blockIdx.x * 128;
  const int bcol = blockIdx.y * 128;

  const int srow = l >> 3;
  const int sslot = l & 7;

  f32x4 acc[4][4] = {};

  for (int k0 = 0; k0 < K; k0 += 64) {
#pragma unroll
    for (int cc = 0; cc < 4; ++cc) {
      int c = w * 4 + cc;
      int row = c * 8 + srow;
      int kswz = (sslot ^ (row & 7)) * 8;
      size_t aoff = (size_t)(brow + row) * K + k0 + kswz;
      size_t boff = (size_t)(bcol + row) * K + k0 + kswz;
      gld16((unsigned*)(sA + c * 512), (const unsigned*)(A + aoff));
      gld16((unsigned*)(sB + c * 512), (const unsigned*)(B + boff));
    }
    __syncthreads();

#pragma unroll
    for (int ks = 0; ks < 2; ++ks) {
      bf16x8 fa[4], fb[4];
#pragma unroll
      for (int i = 0; i < 4; ++i) {
        int arow = wr * 64 + i * 16 + lr;
        int brow_ = wc * 64 + i * 16 + lr;
        fa[i] = *reinterpret_cast<const bf16x8*>(
            &sA[arow * 64 + (((lg + 4 * ks) ^ (arow & 7)) << 3)]);
        fb[i] = *reinterpret_cast<const bf16x8*>(
            &sB[brow_ * 64 + (((lg + 4 * ks) ^ (brow_ & 7)) << 3)]);
      }
#pragma unroll
      for (int mi = 0; mi < 4; ++mi)
#pragma unroll
        for (int ni = 0; ni < 4; ++ni)
          acc[mi][ni] = __builtin_amdgcn_mfma_f32_16x16x32_bf16(
              fa[mi], fb[ni], acc[mi][ni], 0, 0, 0);
    }
    __syncthreads();
  }

  const float qscale = (bcol < EMB) ? 0.125f * LOG2E : 1.0f;
#pragma unroll
  for (int mi = 0; mi < 4; ++mi)
#pragma unroll
    for (int ni = 0; ni < 4; ++ni)
#pragma unroll
      for (int r = 0; r < 4; ++r) {
        size_t m = brow + wr * 64 + mi * 16 + 4 * lg + r;
        size_t n = bcol + wc * 64 + ni * 16 + lr;
        Cb[m * N + n] = f2bf(acc[mi][ni][r] * qscale);
      }
}

// ---------------------------------------------------------------------------
// Output projection GEMM with FUSED split-combine on the A operand:
//   A[q][k] = (Sp0[q][k] + Sp1[q][k]) / (l0[h][q] + l1[h][q]),  h = k/64
// Reg-staged to bf16. Rule-21 layout: global source read at the SWIZZLED
// offset (k0 + kswz), LDS write at the LINEAR lane address (lrow*64+sslot*8)
// -- byte-identical LDS image to the gld16 path; reads keep the XOR swizzle.
// ---------------------------------------------------------------------------
__global__ __launch_bounds__(256) void gemm_out_fused(
    const float* __restrict__ Sp, const float* __restrict__ lp,
    const u16* __restrict__ B, const float* __restrict__ bias,
    float* __restrict__ Cf)
{
  __shared__ __align__(16) u16 sA[128 * 64];
  __shared__ __align__(16) u16 sB[128 * 64];

  constexpr int K = EMB, N = EMB;
  constexpr size_t NSP = (size_t)S_LEN * EMB;

  const int tid  = threadIdx.x;
  const int w    = tid >> 6;
  const int l    = tid & 63;
  const int lg   = l >> 4;
  const int lr   = l & 15;
  const int wr   = w >> 1;
  const int wc   = w & 1;
  const int brow = blockIdx.x * 128;
  const int bcol = blockIdx.y * 128;

  const int srow = l >> 3;
  const int sslot = l & 7;

  f32x4 acc[4][4] = {};

  for (int k0 = 0; k0 < K; k0 += 64) {
    const int h = k0 >> 6;   // head, tile-constant (kswz < 64)
#pragma unroll
    for (int cc = 0; cc < 4; ++cc) {
      int c = w * 4 + cc;
      int lrow = c * 8 + srow;                  // local row 0..127
      int row  = brow + lrow;                   // global q
      int kswz = (sslot ^ (lrow & 7)) * 8;
      // ---- A: reg-stage with fused combine ----
      // source: swizzled global offset; dest: LINEAR lane slot (rule #21).
      const float* p0 = Sp + (size_t)row * EMB + k0 + kswz;
      float4 a0 = *reinterpret_cast<const float4*>(p0);
      float4 a1 = *reinterpret_cast<const float4*>(p0 + 4);
      float4 b0 = *reinterpret_cast<const float4*>(p0 + NSP);
      float4 b1 = *reinterpret_cast<const float4*>(p0 + NSP + 4);
      float inv = 1.0f / (lp[(size_t)h * S_LEN + row] +
                          lp[(size_t)(NH + h) * S_LEN + row]);
      ushort4 h0, h1;
      const float* ap = reinterpret_cast<const float*>(&a0);
      const float* bp = reinterpret_cast<const float*>(&b0);
      const float* cp = reinterpret_cast<const float*>(&a1);
      const float* dp = reinterpret_cast<const float*>(&b1);
#pragma unroll
      for (int j = 0; j < 4; ++j) {
        reinterpret_cast<u16*>(&h0)[j] = f2bf((ap[j] + bp[j]) * inv);
        reinterpret_cast<u16*>(&h1)[j] = f2bf((cp[j] + dp[j]) * inv);
      }
      uint4 pack;
      pack.x = (unsigned)h0.x | ((unsigned)h0.y << 16);
      pack.y = (unsigned)h0.z | ((unsigned)h0.w << 16);
      pack.z = (unsigned)h1.x | ((unsigned)h1.y << 16);
      pack.w = (unsigned)h1.z | ((unsigned)h1.w << 16);
      *reinterpret_cast<uint4*>(&sA[lrow * 64 + sslot * 8]) = pack;  // LINEAR
      // ---- B: gld16 as before ----
      size_t boff = (size_t)(bcol + lrow) * K + k0 + kswz;
      gld16((unsigned*)(sB + c * 512), (const unsigned*)(B + boff));
    }
    __syncthreads();

#pragma unroll
    for (int ks = 0; ks < 2; ++ks) {
      bf16x8 fa[4], fb[4];
#pragma unroll
      for (int i = 0; i < 4; ++i) {
        int arow = wr * 64 + i * 16 + lr;
        int brow_ = wc * 64 + i * 16 + lr;
        fa[i] = *reinterpret_cast<const bf16x8*>(
            &sA[arow * 64 + (((lg + 4 * ks) ^ (arow & 7)) << 3)]);
        fb[i] = *reinterpret_cast<const bf16x8*>(
            &sB[brow_ * 64 + (((lg + 4 * ks) ^ (brow_ & 7)) << 3)]);
      }
#pragma unroll
      for (int mi = 0; mi < 4; ++mi)
#pragma unroll
        for (int ni = 0; ni < 4; ++ni)
          acc[mi][ni] = __builtin_amdgcn_mfma_f32_16x16x32_bf16(
              fa[mi], fb[ni], acc[mi][ni], 0, 0, 0);
    }
    __syncthreads();
  }

#pragma unroll
  for (int mi = 0; mi < 4; ++mi)
#pragma unroll
    for (int ni = 0; ni < 4; ++ni)
#pragma unroll
      for (int r = 0; r < 4; ++r) {
        size_t m = brow + wr * 64 + mi * 16 + 4 * lg + r;
        size_t n = bcol + wc * 64 + ni * 16 + lr;
        Cf[m * N + n] = acc[mi][ni][r] + bias[n];
      }
}

// ---------------------------------------------------------------------------
// Flash attention split-t (R14 structure, verbatim): qf=2, 256 thr (4 waves),
// q-tile 128, 2-phase double-buffered K/V staging, offset-free exp2 softmax,
// O^T accumulation, ones-MFMA row sums, hoisted swizzled offsets, setprio.
// Grid 768 = 12h x 32qt x 2split = 3 blocks/CU = 12 waves/CU. LDS 48KB.
// VGPR must stay <= 128 for 12 waves/CU (measured 84).
// ---------------------------------------------------------------------------
__device__ inline int key7(int row) { return (row ^ (row >> 3)) & 7; }
__device__ inline int swz16(int row, int s) {          // u16 idx; 16B slot s
  return row * 64 + ((s ^ key7(row)) << 3);
}
__device__ inline int swz32(int row, int p) {          // u32 idx; p=0..31
  return row * 32 + ((((p >> 2) ^ key7(row)) << 2) | (p & 3));
}

__global__ __launch_bounds__(256, 3) void flash_split(
    const u16* __restrict__ qkv, float* __restrict__ Sp,
    float* __restrict__ lp)
{
  __shared__ __align__(16) u16 Ks[2][64 * 64];
  __shared__ __align__(16) u16 Vt[2][64 * 64];
  __shared__ __align__(16) u16 Ps[4][32 * 64];

  const int tid = threadIdx.x;
  const int w   = tid >> 6;
  const int l   = tid & 63;
  const int lg  = l >> 4;
  const int lr  = l & 15;

  // XCD swizzle: 768 = 8 x 96 (bijective)
  const int bid   = blockIdx.x;
  const int sbid  = (bid & 7) * 96 + (bid >> 3);
  const int split = sbid & 1;
  const int qb    = ((sbid >> 1) & 31) * 128;
  const int h     = sbid >> 6;            // 0..11
  const int tbeg  = split * TSPLIT;

  unsigned* Pw = (unsigned*)Ps[w];

  const int tq  = tid >> 3;   // 0..31 (V staging: t-pair)
  const int vgs = tid & 7;    // d-slot

  // ---- hoisted per-lane LDS offsets (all loop-invariant) ----
  int kfO[4][2], paO[2][2], pwO[2][4], vcO[8];
#pragma unroll
  for (int tt = 0; tt < 4; ++tt)
#pragma unroll
    for (int ks = 0; ks < 2; ++ks)
      kfO[tt][ks] = swz16(tt * 16 + lr, 4 * ks + lg);
#pragma unroll
  for (int qf = 0; qf < 2; ++qf) {
#pragma unroll
    for (int ks = 0; ks < 2; ++ks)
      paO[qf][ks] = swz16(qf * 16 + lr, 4 * ks + lg);
#pragma unroll
    for (int tt = 0; tt < 4; ++tt)
      pwO[qf][tt] = swz32(qf * 16 + lr, 8 * tt + 2 * lg);
  }
#pragma unroll
  for (int j = 0; j < 8; ++j)
    vcO[j] = swz32(vgs * 8 + j, tq);

  // K-staging lane-constant global offsets (elements)
  const int kt0 = tid >> 3, kg0 = tid & 7;
  const int kgo0 = kt0 * QKV_DIM + ((kg0 ^ key7(kt0)) << 3);
  const int kgo1 = (kt0 + 32) * QKV_DIM + ((kg0 ^ key7(kt0 + 32)) << 3);

  const u16* kg = qkv + EMB + h * DK + (size_t)tbeg * QKV_DIM;
  const u16* vg = qkv + 2 * EMB + h * DK +
                  ((size_t)tbeg + 2 * tq) * QKV_DIM + vgs * 8;

  // Q fragments (MFMA B-operand: col=lr -> q, k = d = ks*32 + lg*8 + j)
  bf16x8 qfr[2][2];
#pragma unroll
  for (int qf = 0; qf < 2; ++qf)
#pragma unroll
    for (int ks = 0; ks < 2; ++ks)
      qfr[qf][ks] = *reinterpret_cast<const bf16x8*>(
          qkv + (size_t)(qb + w * 32 + qf * 16 + lr) * QKV_DIM + h * DK + ks * 32 + lg * 8);

  bf16x8 ones;
#pragma unroll
  for (int i = 0; i < 8; ++i) ones[i] = (short)0x3F80;   // bf16 1.0

  f32x4 acc[2][4] = {};
  f32x4 lacc[2]   = {};
  uint4 vr0, vr1;             // V rows {2tq, 2tq+1} in flight

  // ---- prologue: stage tile 0 (K -> LDS gld, V -> regs) ----
  gld16((unsigned*)(Ks[0] + tid * 8),        (const unsigned*)(kg + kgo0));
  gld16((unsigned*)(Ks[0] + 2048 + tid * 8), (const unsigned*)(kg + kgo1));
  vr0 = *reinterpret_cast<const uint4*>(vg);
  vr1 = *reinterpret_cast<const uint4*>(vg + QKV_DIM);

  constexpr int NT = TSPLIT / 64;   // 32

#define FL_ITER(CUR, IT)                                                       \
  {                                                                            \
    /* phase A: commit in-flight V regs to Vt[CUR] */                          \
    {                                                                          \
      unsigned* vdst = (unsigned*)Vt[CUR];                                     \
      const unsigned* a0 = reinterpret_cast<const unsigned*>(&vr0);            \
      const unsigned* a1 = reinterpret_cast<const unsigned*>(&vr1);            \
      _Pragma("unroll")                                                        \
      for (int j = 0; j < 8; ++j) {                                            \
        unsigned sel = (j & 1) ? 0x07060302u : 0x05040100u;                    \
        vdst[vcO[j]] = __builtin_amdgcn_perm(a1[j >> 1], a0[j >> 1], sel);     \
      }                                                                        \
    }                                                                          \
    __syncthreads();                                                           \
    /* phase B: issue next tile's loads */                                     \
    if ((IT) + 1 < NT) {                                                       \
      kg += 64 * QKV_DIM;                                                      \
      vg += 64 * QKV_DIM;                                                      \
      gld16((unsigned*)(Ks[(CUR) ^ 1] + tid * 8),                              \
            (const unsigned*)(kg + kgo0));                                     \
      gld16((unsigned*)(Ks[(CUR) ^ 1] + 2048 + tid * 8),                       \
            (const unsigned*)(kg + kgo1));                                     \
      vr0 = *reinterpret_cast<const uint4*>(vg);                               \
      vr1 = *reinterpret_cast<const uint4*>(vg + QKV_DIM);                     \
    }                                                                          \
    /* phase C: compute on buf CUR */                                          \
    {                                                                          \
      bf16x8 kf[4][2];                                                         \
      _Pragma("unroll")                                                        \
      for (int tt = 0; tt < 4; ++tt) {                                         \
        kf[tt][0] = *reinterpret_cast<const bf16x8*>(&Ks[CUR][kfO[tt][0]]);    \
        kf[tt][1] = *reinterpret_cast<const bf16x8*>(&Ks[CUR][kfO[tt][1]]);    \
      }                                                                        \
      _Pragma("unroll")                                                        \
      for (int qf = 0; qf < 2; ++qf) {                                         \
        f32x4 s[4] = {};                                                       \
        __builtin_amdgcn_s_setprio(1);                                         \
        _Pragma("unroll")                                                      \
        for (int tt = 0; tt < 4; ++tt) {                                       \
          s[tt] = __builtin_amdgcn_mfma_f32_16x16x32_bf16(                     \
              kf[tt][0], qfr[qf][0], s[tt], 0, 0, 0);                          \
          s[tt] = __builtin_amdgcn_mfma_f32_16x16x32_bf16(                     \
              kf[tt][1], qfr[qf][1], s[tt], 0, 0, 0);                          \
        }                                                                      \
        __builtin_amdgcn_s_setprio(0);                                         \
        _Pragma("unroll")                                                      \
        for (int tt = 0; tt < 4; ++tt) {                                       \
          float p0 = fast_exp2(s[tt][0]);                                      \
          float p1 = fast_exp2(s[tt][1]);                                      \
          float p2 = fast_exp2(s[tt][2]);                                      \
          float p3 = fast_exp2(s[tt][3]);                                      \
          uint2 pv;                                                            \
          pv.x = __builtin_amdgcn_perm(__float_as_uint(p1),                    \
                                       __float_as_uint(p0), 0x07060302u);      \
          pv.y = __builtin_amdgcn_perm(__float_as_uint(p3),                    \
                                       __float_as_uint(p2), 0x07060302u);      \
          *reinterpret_cast<uint2*>(&Pw[pwO[qf][tt]]) = pv;                    \
        }                                                                      \
      }                                                                        \
      __builtin_amdgcn_s_setprio(1);                                           \
      _Pragma("unroll")                                                        \
      for (int ks = 0; ks < 2; ++ks) {                                         \
        bf16x8 pa[2];                                                          \
        pa[0] = *reinterpret_cast<const bf16x8*>(&Ps[w][paO[0][ks]]);          \
        pa[1] = *reinterpret_cast<const bf16x8*>(&Ps[w][paO[1][ks]]);          \
        lacc[0] = __builtin_amdgcn_mfma_f32_16x16x32_bf16(                     \
            ones, pa[0], lacc[0], 0, 0, 0);                                    \
        lacc[1] = __builtin_amdgcn_mfma_f32_16x16x32_bf16(                     \
            ones, pa[1], lacc[1], 0, 0, 0);                                    \
        _Pragma("unroll")                                                      \
        for (int dt = 0; dt < 4; ++dt) {                                       \
          bf16x8 vf = *reinterpret_cast<const bf16x8*>(&Vt[CUR][kfO[dt][ks]]); \
          acc[0][dt] = __builtin_amdgcn_mfma_f32_16x16x32_bf16(                \
              vf, pa[0], acc[0][dt], 0, 0, 0);                                 \
          acc[1][dt] = __builtin_amdgcn_mfma_f32_16x16x32_bf16(                \
              vf, pa[1], acc[1][dt], 0, 0, 0);                                 \
        }                                                                      \
      }                                                                        \
      __builtin_amdgcn_s_setprio(0);                                           \
    }                                                                          \
  }

  for (int it = 0; it < NT; it += 2) {
    FL_ITER(0, it);
    FL_ITER(1, it + 1);
  }
#undef FL_ITER

  // ---- epilogue: store partial O (f32) + row sum l (from ones-MFMA) ----
#pragma unroll
  for (int qf = 0; qf < 2; ++qf) {
    int q = qb + w * 32 + qf * 16 + lr;
    size_t base = ((size_t)split * S_LEN + q) * EMB + h * DK;
#pragma unroll
    for (int dt = 0; dt < 4; ++dt)
      *reinterpret_cast<float4*>(&Sp[base + dt * 16 + 4 * lg]) =
          *reinterpret_cast<float4*>(&acc[qf][dt]);
    if (lg == 0)
      lp[((size_t)split * NH + h) * S_LEN + q] = lacc[qf][0];
  }
}

// ---------------------------------------------------------------------------
extern "C" void kernel_launch(void* const* d_in, const int* in_sizes, int n_in,
                              void* d_out, int out_size, void* d_ws, size_t ws_size,
                              hipStream_t stream) {
  const float* x     = (const float*)d_in[0];
  const float* w_qkv = (const float*)d_in[1];
  const float* w_out = (const float*)d_in[2];
  const float* b_out = (const float*)d_in[3];
  float* out = (float*)d_out;

  constexpr size_t NX  = (size_t)S_LEN * EMB;
  constexpr size_t NWQ = (size_t)QKV_DIM * EMB;
  constexpr size_t NWO = (size_t)EMB * EMB;
  constexpr size_t NQ  = (size_t)S_LEN * QKV_DIM;

  u16* xb    = (u16*)d_ws;
  u16* wqb   = xb + NX;
  u16* wob   = wqb + NWQ;
  u16* qkvb  = wob + NWO;
  float* Sp  = (float*)(qkvb + NQ);                 // 2 x [4096][768] f32
  float* lp  = Sp + (size_t)NSPLIT * S_LEN * EMB;   // 2 x [12][4096] f32

  dim3 blk(256);

  cast_bf16_fused<<<dim3(896), blk, 0, stream>>>(
      x, xb, (int)(NX / 8), w_qkv, wqb, (int)(NWQ / 8), w_out, wob, (int)(NWO / 8));

  // qkv = x @ w_qkv^T (bf16 out, Q pre-scaled 0.125*log2e)
  gemm_qkv<<<dim3(S_LEN / 128, QKV_DIM / 128), blk, 0, stream>>>(
      xb, wqb, qkvb, S_LEN, QKV_DIM, EMB);

  // attention split partials
  flash_split<<<dim3(768), blk, 0, stream>>>(qkvb, Sp, lp);

  // out = combine(Sp, lp) @ w_out^T + b_out (combine fused into A-staging)
  gemm_out_fused<<<dim3(S_LEN / 128, EMB / 128), blk, 0, stream>>>(
      Sp, lp, wob, b_out, out);
}

// Round 17
// 121.486 us; speedup vs baseline: 1.0468x; 1.0468x over previous
//
#include <hip/hip_runtime.h>
#include <hip/hip_bf16.h>

constexpr int S_LEN   = 4096;
constexpr int EMB     = 768;
constexpr int NH      = 12;
constexpr int DK      = 64;
constexpr int QKV_DIM = 3 * EMB;   // 2304
constexpr int NSPLIT  = 2;
constexpr int TSPLIT  = S_LEN / NSPLIT;  // 2048

typedef short bf16x8 __attribute__((ext_vector_type(8)));
typedef float f32x4  __attribute__((ext_vector_type(4)));
typedef unsigned short u16;

// f32 -> bf16 round-to-nearest-even (cold paths / GEMM epilogues)
__device__ inline u16 f2bf(float x) {
  unsigned u = __float_as_uint(x);
  unsigned r = u + 0x7fffu + ((u >> 16) & 1u);
  return (u16)(r >> 16);
}
__device__ inline float bf2f(u16 h) {
  return __uint_as_float(((unsigned)h) << 16);
}

__device__ inline void gld16(unsigned* lds, const unsigned* g) {
  __builtin_amdgcn_global_load_lds(
      (const __attribute__((address_space(1))) unsigned*)g,
      (__attribute__((address_space(3))) unsigned*)lds, 16, 0, 0);
}

// raw v_exp_f32 (2^x); scores are bounded, no special-case handling needed
__device__ inline float fast_exp2(float x) {
  float r;
  asm("v_exp_f32 %0, %1" : "=v"(r) : "v"(x));
  return r;
}

#define LOG2E 1.4426950408889634f

// ---------------------------------------------------------------------------
// fused fp32 -> bf16 casts for x, w_qkv, w_out (one launch, 3 grid segments)
// ---------------------------------------------------------------------------
__global__ __launch_bounds__(256) void cast_bf16_fused(
    const float* __restrict__ s0, u16* __restrict__ d0, int n0,   // 512 blocks
    const float* __restrict__ s1, u16* __restrict__ d1, int n1,   // 256 blocks
    const float* __restrict__ s2, u16* __restrict__ d2, int n2)   // 128 blocks
{
  const float* src; u16* dst; int n8, b0, nb;
  if (blockIdx.x < 512)      { src = s0; dst = d0; n8 = n0; b0 = 0;   nb = 512; }
  else if (blockIdx.x < 768) { src = s1; dst = d1; n8 = n1; b0 = 512; nb = 256; }
  else                       { src = s2; dst = d2; n8 = n2; b0 = 768; nb = 128; }
  for (int i = (blockIdx.x - b0) * 256 + threadIdx.x; i < n8; i += nb * 256) {
    float4 a = reinterpret_cast<const float4*>(src)[2 * i + 0];
    float4 b = reinterpret_cast<const float4*>(src)[2 * i + 1];
    ushort4 h0, h1;
    const float* ap = reinterpret_cast<const float*>(&a);
    const float* bp = reinterpret_cast<const float*>(&b);
#pragma unroll
    for (int j = 0; j < 4; ++j) {
      reinterpret_cast<u16*>(&h0)[j] = f2bf(ap[j]);
      reinterpret_cast<u16*>(&h1)[j] = f2bf(bp[j]);
    }
    reinterpret_cast<ushort4*>(dst)[2 * i + 0] = h0;
    reinterpret_cast<ushort4*>(dst)[2 * i + 1] = h1;
  }
}

// ---------------------------------------------------------------------------
// bf16 NT-GEMM: C[M,N] = A[M,K] @ B[N,K]^T, fp32 accum.
// MODE 0: bf16 out; Q cols (<EMB) scaled by 0.125*log2(e). MODE 1: f32+bias.
// ---------------------------------------------------------------------------
template<int MODE>
__global__ __launch_bounds__(256) void gemm_bf16_nt(
    const u16* __restrict__ A, const u16* __restrict__ B,
    const float* __restrict__ bias,
    u16* __restrict__ Cb, float* __restrict__ Cf,
    int M, int N, int K)
{
  __shared__ __align__(16) u16 sA[128 * 64];
  __shared__ __align__(16) u16 sB[128 * 64];

  const int tid  = threadIdx.x;
  const int w    = tid >> 6;
  const int l    = tid & 63;
  const int lg   = l >> 4;
  const int lr   = l & 15;
  const int wr   = w >> 1;
  const int wc   = w & 1;
  const int brow = blockIdx.x * 128;
  const int bcol = blockIdx.y * 128;

  const int srow = l >> 3;
  const int sslot = l & 7;

  f32x4 acc[4][4] = {};

  for (int k0 = 0; k0 < K; k0 += 64) {
#pragma unroll
    for (int cc = 0; cc < 4; ++cc) {
      int c = w * 4 + cc;
      int row = c * 8 + srow;
      int kswz = (sslot ^ (row & 7)) * 8;
      size_t aoff = (size_t)(brow + row) * K + k0 + kswz;
      size_t boff = (size_t)(bcol + row) * K + k0 + kswz;
      gld16((unsigned*)(sA + c * 512), (const unsigned*)(A + aoff));
      gld16((unsigned*)(sB + c * 512), (const unsigned*)(B + boff));
    }
    __syncthreads();

#pragma unroll
    for (int ks = 0; ks < 2; ++ks) {
      bf16x8 fa[4], fb[4];
#pragma unroll
      for (int i = 0; i < 4; ++i) {
        int arow = wr * 64 + i * 16 + lr;
        int brow_ = wc * 64 + i * 16 + lr;
        fa[i] = *reinterpret_cast<const bf16x8*>(
            &sA[arow * 64 + (((lg + 4 * ks) ^ (arow & 7)) << 3)]);
        fb[i] = *reinterpret_cast<const bf16x8*>(
            &sB[brow_ * 64 + (((lg + 4 * ks) ^ (brow_ & 7)) << 3)]);
      }
#pragma unroll
      for (int mi = 0; mi < 4; ++mi)
#pragma unroll
        for (int ni = 0; ni < 4; ++ni)
          acc[mi][ni] = __builtin_amdgcn_mfma_f32_16x16x32_bf16(
              fa[mi], fb[ni], acc[mi][ni], 0, 0, 0);
    }
    __syncthreads();
  }

  if (MODE == 0) {
    const float qscale = (bcol < EMB) ? 0.125f * LOG2E : 1.0f;
#pragma unroll
    for (int mi = 0; mi < 4; ++mi)
#pragma unroll
      for (int ni = 0; ni < 4; ++ni)
#pragma unroll
        for (int r = 0; r < 4; ++r) {
          size_t m = brow + wr * 64 + mi * 16 + 4 * lg + r;
          size_t n = bcol + wc * 64 + ni * 16 + lr;
          Cb[m * N + n] = f2bf(acc[mi][ni][r] * qscale);
        }
  } else {
#pragma unroll
    for (int mi = 0; mi < 4; ++mi)
#pragma unroll
      for (int ni = 0; ni < 4; ++ni)
#pragma unroll
        for (int r = 0; r < 4; ++r) {
          size_t m = brow + wr * 64 + mi * 16 + 4 * lg + r;
          size_t n = bcol + wc * 64 + ni * 16 + lr;
          Cf[m * N + n] = acc[mi][ni][r] + bias[n];
        }
  }
}

// ---------------------------------------------------------------------------
// Flash attention split-t (R11/R14 structure): qf=2, 256 thr (4 waves),
// q-tile 128, 2-phase double-buffered K/V staging, offset-free exp2 softmax,
// O^T accumulation, ones-MFMA row sums, hoisted swizzled offsets, setprio.
// Grid 768 = 12h x 32qt x 2split = 3 blocks/CU = 12 waves/CU. LDS 48KB.
// VGPR must stay <= 128 for 12 waves/CU (measured 84).
// ---------------------------------------------------------------------------
__device__ inline int key7(int row) { return (row ^ (row >> 3)) & 7; }
__device__ inline int swz16(int row, int s) {          // u16 idx; 16B slot s
  return row * 64 + ((s ^ key7(row)) << 3);
}
__device__ inline int swz32(int row, int p) {          // u32 idx; p=0..31
  return row * 32 + ((((p >> 2) ^ key7(row)) << 2) | (p & 3));
}

__global__ __launch_bounds__(256, 3) void flash_split(
    const u16* __restrict__ qkv, float* __restrict__ Sp,
    float* __restrict__ lp)
{
  __shared__ __align__(16) u16 Ks[2][64 * 64];
  __shared__ __align__(16) u16 Vt[2][64 * 64];
  __shared__ __align__(16) u16 Ps[4][32 * 64];

  const int tid = threadIdx.x;
  const int w   = tid >> 6;
  const int l   = tid & 63;
  const int lg  = l >> 4;
  const int lr  = l & 15;

  // XCD swizzle: 768 = 8 x 96 (bijective)
  const int bid   = blockIdx.x;
  const int sbid  = (bid & 7) * 96 + (bid >> 3);
  const int split = sbid & 1;
  const int qb    = ((sbid >> 1) & 31) * 128;
  const int h     = sbid >> 6;            // 0..11
  const int tbeg  = split * TSPLIT;

  unsigned* Pw = (unsigned*)Ps[w];

  const int tq  = tid >> 3;   // 0..31 (V staging: t-pair)
  const int vgs = tid & 7;    // d-slot

  // ---- hoisted per-lane LDS offsets (all loop-invariant) ----
  int kfO[4][2], paO[2][2], pwO[2][4], vcO[8];
#pragma unroll
  for (int tt = 0; tt < 4; ++tt)
#pragma unroll
    for (int ks = 0; ks < 2; ++ks)
      kfO[tt][ks] = swz16(tt * 16 + lr, 4 * ks + lg);
#pragma unroll
  for (int qf = 0; qf < 2; ++qf) {
#pragma unroll
    for (int ks = 0; ks < 2; ++ks)
      paO[qf][ks] = swz16(qf * 16 + lr, 4 * ks + lg);
#pragma unroll
    for (int tt = 0; tt < 4; ++tt)
      pwO[qf][tt] = swz32(qf * 16 + lr, 8 * tt + 2 * lg);
  }
#pragma unroll
  for (int j = 0; j < 8; ++j)
    vcO[j] = swz32(vgs * 8 + j, tq);

  // K-staging lane-constant global offsets (elements)
  const int kt0 = tid >> 3, kg0 = tid & 7;
  const int kgo0 = kt0 * QKV_DIM + ((kg0 ^ key7(kt0)) << 3);
  const int kgo1 = (kt0 + 32) * QKV_DIM + ((kg0 ^ key7(kt0 + 32)) << 3);

  const u16* kg = qkv + EMB + h * DK + (size_t)tbeg * QKV_DIM;
  const u16* vg = qkv + 2 * EMB + h * DK +
                  ((size_t)tbeg + 2 * tq) * QKV_DIM + vgs * 8;

  // Q fragments (MFMA B-operand: col=lr -> q, k = d = ks*32 + lg*8 + j)
  bf16x8 qfr[2][2];
#pragma unroll
  for (int qf = 0; qf < 2; ++qf)
#pragma unroll
    for (int ks = 0; ks < 2; ++ks)
      qfr[qf][ks] = *reinterpret_cast<const bf16x8*>(
          qkv + (size_t)(qb + w * 32 + qf * 16 + lr) * QKV_DIM + h * DK + ks * 32 + lg * 8);

  bf16x8 ones;
#pragma unroll
  for (int i = 0; i < 8; ++i) ones[i] = (short)0x3F80;   // bf16 1.0

  f32x4 acc[2][4] = {};
  f32x4 lacc[2]   = {};
  uint4 vr0, vr1;             // V rows {2tq, 2tq+1} in flight

  // ---- prologue: stage tile 0 (K -> LDS gld, V -> regs) ----
  gld16((unsigned*)(Ks[0] + tid * 8),        (const unsigned*)(kg + kgo0));
  gld16((unsigned*)(Ks[0] + 2048 + tid * 8), (const unsigned*)(kg + kgo1));
  vr0 = *reinterpret_cast<const uint4*>(vg);
  vr1 = *reinterpret_cast<const uint4*>(vg + QKV_DIM);

  constexpr int NT = TSPLIT / 64;   // 32

#define FL_ITER(CUR, IT)                                                       \
  {                                                                            \
    /* phase A: commit in-flight V regs to Vt[CUR] */                          \
    {                                                                          \
      unsigned* vdst = (unsigned*)Vt[CUR];                                     \
      const unsigned* a0 = reinterpret_cast<const unsigned*>(&vr0);            \
      const unsigned* a1 = reinterpret_cast<const unsigned*>(&vr1);            \
      _Pragma("unroll")                                                        \
      for (int j = 0; j < 8; ++j) {                                            \
        unsigned sel = (j & 1) ? 0x07060302u : 0x05040100u;                    \
        vdst[vcO[j]] = __builtin_amdgcn_perm(a1[j >> 1], a0[j >> 1], sel);     \
      }                                                                        \
    }                                                                          \
    __syncthreads();                                                           \
    /* phase B: issue next tile's loads */                                     \
    if ((IT) + 1 < NT) {                                                       \
      kg += 64 * QKV_DIM;                                                      \
      vg += 64 * QKV_DIM;                                                      \
      gld16((unsigned*)(Ks[(CUR) ^ 1] + tid * 8),                              \
            (const unsigned*)(kg + kgo0));                                     \
      gld16((unsigned*)(Ks[(CUR) ^ 1] + 2048 + tid * 8),                       \
            (const unsigned*)(kg + kgo1));                                     \
      vr0 = *reinterpret_cast<const uint4*>(vg);                               \
      vr1 = *reinterpret_cast<const uint4*>(vg + QKV_DIM);                     \
    }                                                                          \
    /* phase C: compute on buf CUR */                                          \
    {                                                                          \
      bf16x8 kf[4][2];                                                         \
      _Pragma("unroll")                                                        \
      for (int tt = 0; tt < 4; ++tt) {                                         \
        kf[tt][0] = *reinterpret_cast<const bf16x8*>(&Ks[CUR][kfO[tt][0]]);    \
        kf[tt][1] = *reinterpret_cast<const bf16x8*>(&Ks[CUR][kfO[tt][1]]);    \
      }                                                                        \
      _Pragma("unroll")                                                        \
      for (int qf = 0; qf < 2; ++qf) {                                         \
        f32x4 s[4] = {};                                                       \
        __builtin_amdgcn_s_setprio(1);                                         \
        _Pragma("unroll")                                                      \
        for (int tt = 0; tt < 4; ++tt) {                                       \
          s[tt] = __builtin_amdgcn_mfma_f32_16x16x32_bf16(                     \
              kf[tt][0], qfr[qf][0], s[tt], 0, 0, 0);                          \
          s[tt] = __builtin_amdgcn_mfma_f32_16x16x32_bf16(                     \
              kf[tt][1], qfr[qf][1], s[tt], 0, 0, 0);                          \
        }                                                                      \
        __builtin_amdgcn_s_setprio(0);                                         \
        _Pragma("unroll")                                                      \
        for (int tt = 0; tt < 4; ++tt) {                                       \
          float p0 = fast_exp2(s[tt][0]);                                      \
          float p1 = fast_exp2(s[tt][1]);                                      \
          float p2 = fast_exp2(s[tt][2]);                                      \
          float p3 = fast_exp2(s[tt][3]);                                      \
          uint2 pv;                                                            \
          pv.x = __builtin_amdgcn_perm(__float_as_uint(p1),                    \
                                       __float_as_uint(p0), 0x07060302u);      \
          pv.y = __builtin_amdgcn_perm(__float_as_uint(p3),                    \
                                       __float_as_uint(p2), 0x07060302u);      \
          *reinterpret_cast<uint2*>(&Pw[pwO[qf][tt]]) = pv;                    \
        }                                                                      \
      }                                                                        \
      __builtin_amdgcn_s_setprio(1);                                           \
      _Pragma("unroll")                                                        \
      for (int ks = 0; ks < 2; ++ks) {                                         \
        bf16x8 pa[2];                                                          \
        pa[0] = *reinterpret_cast<const bf16x8*>(&Ps[w][paO[0][ks]]);          \
        pa[1] = *reinterpret_cast<const bf16x8*>(&Ps[w][paO[1][ks]]);          \
        lacc[0] = __builtin_amdgcn_mfma_f32_16x16x32_bf16(                     \
            ones, pa[0], lacc[0], 0, 0, 0);                                    \
        lacc[1] = __builtin_amdgcn_mfma_f32_16x16x32_bf16(                     \
            ones, pa[1], lacc[1], 0, 0, 0);                                    \
        _Pragma("unroll")                                                      \
        for (int dt = 0; dt < 4; ++dt) {                                       \
          bf16x8 vf = *reinterpret_cast<const bf16x8*>(&Vt[CUR][kfO[dt][ks]]); \
          acc[0][dt] = __builtin_amdgcn_mfma_f32_16x16x32_bf16(                \
              vf, pa[0], acc[0][dt], 0, 0, 0);                                 \
          acc[1][dt] = __builtin_amdgcn_mfma_f32_16x16x32_bf16(                \
              vf, pa[1], acc[1][dt], 0, 0, 0);                                 \
        }                                                                      \
      }                                                                        \
      __builtin_amdgcn_s_setprio(0);                                           \
    }                                                                          \
  }

  for (int it = 0; it < NT; it += 2) {
    FL_ITER(0, it);
    FL_ITER(1, it + 1);
  }
#undef FL_ITER

  // ---- epilogue: store partial O (f32) + row sum l (from ones-MFMA) ----
#pragma unroll
  for (int qf = 0; qf < 2; ++qf) {
    int q = qb + w * 32 + qf * 16 + lr;
    size_t base = ((size_t)split * S_LEN + q) * EMB + h * DK;
#pragma unroll
    for (int dt = 0; dt < 4; ++dt)
      *reinterpret_cast<float4*>(&Sp[base + dt * 16 + 4 * lg]) =
          *reinterpret_cast<float4*>(&acc[qf][dt]);
    if (lg == 0)
      lp[((size_t)split * NH + h) * S_LEN + q] = lacc[qf][0];
  }
}

// ---------------------------------------------------------------------------
// Combine: O = (S0+S1)/(l0+l1) (splits share the implicit offset).
// ---------------------------------------------------------------------------
__global__ __launch_bounds__(256) void combine_splits(
    const float* __restrict__ Sp, const float* __restrict__ lp,
    u16* __restrict__ ao)
{
  constexpr int N4 = S_LEN * EMB / 4;
  for (int i = blockIdx.x * 256 + threadIdx.x; i < N4; i += gridDim.x * 256) {
    int q = i / 192;
    int t = i - q * 192;
    int h = t >> 4;
    float la = lp[(size_t)h * S_LEN + q];
    float lb = lp[(size_t)(NH + h) * S_LEN + q];
    float inv = 1.0f / (la + lb);
    float4 s0 = reinterpret_cast<const float4*>(Sp)[i];
    float4 s1 = reinterpret_cast<const float4*>(Sp)[N4 + i];
    ushort4 o;
    o.x = f2bf((s0.x + s1.x) * inv);
    o.y = f2bf((s0.y + s1.y) * inv);
    o.z = f2bf((s0.z + s1.z) * inv);
    o.w = f2bf((s0.w + s1.w) * inv);
    reinterpret_cast<ushort4*>(ao)[i] = o;
  }
}

// ---------------------------------------------------------------------------
extern "C" void kernel_launch(void* const* d_in, const int* in_sizes, int n_in,
                              void* d_out, int out_size, void* d_ws, size_t ws_size,
                              hipStream_t stream) {
  const float* x     = (const float*)d_in[0];
  const float* w_qkv = (const float*)d_in[1];
  const float* w_out = (const float*)d_in[2];
  const float* b_out = (const float*)d_in[3];
  float* out = (float*)d_out;

  constexpr size_t NX  = (size_t)S_LEN * EMB;
  constexpr size_t NWQ = (size_t)QKV_DIM * EMB;
  constexpr size_t NWO = (size_t)EMB * EMB;
  constexpr size_t NQ  = (size_t)S_LEN * QKV_DIM;

  u16* xb    = (u16*)d_ws;
  u16* wqb   = xb + NX;
  u16* wob   = wqb + NWQ;
  u16* qkvb  = wob + NWO;
  float* Sp  = (float*)(qkvb + NQ);                 // 2 x [4096][768] f32
  float* lp  = Sp + (size_t)NSPLIT * S_LEN * EMB;   // 2 x [12][4096] f32
  u16* aob   = xb;   // alias: x planes dead after QKV GEMM

  dim3 blk(256);

  cast_bf16_fused<<<dim3(896), blk, 0, stream>>>(
      x, xb, (int)(NX / 8), w_qkv, wqb, (int)(NWQ / 8), w_out, wob, (int)(NWO / 8));

  // qkv = x @ w_qkv^T (bf16 out, Q pre-scaled 0.125*log2e)
  gemm_bf16_nt<0><<<dim3(S_LEN / 128, QKV_DIM / 128), blk, 0, stream>>>(
      xb, wqb, nullptr, qkvb, nullptr, S_LEN, QKV_DIM, EMB);

  // attention split partials -> combine to bf16
  flash_split<<<dim3(768), blk, 0, stream>>>(qkvb, Sp, lp);
  combine_splits<<<dim3(1024), blk, 0, stream>>>(Sp, lp, aob);

  // out = attn @ w_out^T + b_out (fp32)
  gemm_bf16_nt<1><<<dim3(S_LEN / 128, EMB / 128), blk, 0, stream>>>(
      aob, wob, b_out, nullptr, out, S_LEN, EMB, EMB);
}